// Round 15
// baseline (63.094 us; speedup 1.0000x reference)
//
#include <hip/hip_runtime.h>

// r14 (59.6 us best) byte-identical EXCEPT: shbuf padded to 10112 floats so
// LDS_Block ~41.2 KB. LLVM's register-allocator occupancy target comes from
// LDS size (getOccupancyWithLocalMemSize): 19.4 KB -> targets 8 blocks/CU ->
// 64 VGPR -> spills keep[16] (r10-r14: WRITE 156-179 MB vs 134 ideal).
// 41.2 KB -> targets 3 blocks/CU -> ~170 VGPR budget -> no spill. Achieved
// occupancy is ~12 waves/CU today anyway, so nothing real is lost.
//  phase 1: 16 chunks of 8 ch through XOR-swizzled slab, 2-deep reg prefetch,
//           9 sums S_d = sum_c p[x]*p[x+d], retain center quads in keep[16].
//  phase 2: inv = 1/sqrt(S_center) (+halo), sim = (1/9)*inv*sum_d inv[x+d]*S_d.
//  phase 3: aligned stride-36 exchange tile (r14-verified).

__device__ __forceinline__ float dot4acc(float4 a, float4 b, float acc) {
    acc = fmaf(a.x, b.x, acc);
    acc = fmaf(a.y, b.y, acc);
    acc = fmaf(a.z, b.z, acc);
    acc = fmaf(a.w, b.w, acc);
    return acc;
}

__global__ __launch_bounds__(256) void bcim_fused(const float* __restrict__ p,
                                                  float* __restrict__ out) {
    __shared__ float shbuf[10112];  // phase1: slab (1536 f); phase3: T[128][36] (4608 f); rest = pad
    __shared__ float invL[192];

    const int tid = threadIdx.x;
    const int b  = blockIdx.x >> 3;
    const int r0 = (blockIdx.x & 7) << 2;
    const float* __restrict__ pb = p + (size_t)b * 131072;
    float* slab = shbuf;

    // ---- loader mapping (v3-verified) ----
    const int l_wq = tid & 7;
    const int l_c  = (tid >> 3) & 7;
    const int l_r  = tid >> 6;
    const int g0r  = r0 - 1 + l_r;
    const int g1r  = r0 + 3 + l_r;
    const bool in0 = ((unsigned)g0r < 32u);
    const bool in1 = (tid < 128) && ((unsigned)g1r < 32u);
    int wOff[4];
    {
        const int chh = l_c >> 2;
        const int ci  = l_c & 3;
        #pragma unroll
        for (int j = 0; j < 4; ++j) {
            const int u = ((l_wq << 3) + (j << 1) + chh) ^ l_wq;
            wOff[j] = l_r * 256 + u * 4 + ci;
        }
    }
    const int gOff0 = l_c * 1024 + g0r * 32 + l_wq * 4;
    const int gOff1 = l_c * 1024 + g1r * 32 + l_wq * 4;

    // ---- stencil mapping (v3-verified) ----
    const int chalf = tid & 1;
    const int pos   = tid >> 1;
    const int h     = pos >> 5;
    const int w     = pos & 31;
    const int wm    = (w > 0) ? w - 1 : 0;
    const int wp    = (w < 31) ? w + 1 : 31;
    const int uc    = (w  * 2 + chalf) ^ (w  >> 2);
    const int um    = (wm * 2 + chalf) ^ (wm >> 2);
    const int up    = (wp * 2 + chalf) ^ (wp >> 2);

    // 2-deep prefetch (A = even chunks, B = odd chunks)
    float4 A0 = make_float4(0.f,0.f,0.f,0.f), A1 = A0, B0 = A0, B1 = A0;
    if (in0) A0 = *(const float4*)(pb + gOff0);
    if (in1) A1 = *(const float4*)(pb + gOff1);
    if (in0) B0 = *(const float4*)(pb + 8192 + gOff0);
    if (in1) B1 = *(const float4*)(pb + 8192 + gOff1);

    float s0=0.f,s1=0.f,s2=0.f,s3=0.f,s4=0.f,s5=0.f,s6=0.f,s7=0.f,s8=0.f,hn=0.f;
    float4 keep[16];

    #define STEP(R0, R1, NEXTC, CUR) {                                              \
        slab[wOff[0]] = R0.x; slab[wOff[1]] = R0.y;                                 \
        slab[wOff[2]] = R0.z; slab[wOff[3]] = R0.w;                                 \
        if (tid < 128) {                                                            \
            slab[wOff[0] + 1024] = R1.x; slab[wOff[1] + 1024] = R1.y;               \
            slab[wOff[2] + 1024] = R1.z; slab[wOff[3] + 1024] = R1.w;               \
        }                                                                           \
        __syncthreads();                                                            \
        if ((NEXTC) < 16) {                                                         \
            if (in0) R0 = *(const float4*)(pb + (NEXTC) * 8192 + gOff0);            \
            if (in1) R1 = *(const float4*)(pb + (NEXTC) * 8192 + gOff1);            \
        }                                                                           \
        {                                                                           \
            const float4* sp = (const float4*)slab;                                 \
            const float4 ctr = sp[(h + 1) * 64 + uc];                               \
            keep[CUR] = ctr;                                                        \
            float4 n0 = sp[h * 64 + um];                                            \
            float4 n1 = sp[h * 64 + uc];                                            \
            float4 n2 = sp[h * 64 + up];                                            \
            s0 = dot4acc(ctr, n0, s0);                                              \
            s1 = dot4acc(ctr, n1, s1);                                              \
            s2 = dot4acc(ctr, n2, s2);                                              \
            if (h == 0) hn = dot4acc(n1, n1, hn);                                   \
            n0 = sp[(h + 2) * 64 + um];                                             \
            n1 = sp[(h + 2) * 64 + uc];                                             \
            n2 = sp[(h + 2) * 64 + up];                                             \
            s6 = dot4acc(ctr, n0, s6);                                              \
            s7 = dot4acc(ctr, n1, s7);                                              \
            s8 = dot4acc(ctr, n2, s8);                                              \
            if (h == 3) hn = dot4acc(n1, n1, hn);                                   \
            n0 = sp[(h + 1) * 64 + um];                                             \
            n2 = sp[(h + 1) * 64 + up];                                             \
            s3 = dot4acc(ctr, n0, s3);                                              \
            s4 = dot4acc(ctr, ctr, s4);                                             \
            s5 = dot4acc(ctr, n2, s5);                                              \
        }                                                                           \
        __syncthreads(); }

    #pragma unroll
    for (int ch = 0; ch < 16; ch += 2) {
        STEP(A0, A1, ch + 2, ch)
        STEP(B0, B1, ch + 3, ch + 1)
    }
    #undef STEP

    // pair-reduce channel halves (lanes 2k <-> 2k+1): both lanes get full sums
    s0 += __shfl_xor(s0, 1); s1 += __shfl_xor(s1, 1); s2 += __shfl_xor(s2, 1);
    s3 += __shfl_xor(s3, 1); s4 += __shfl_xor(s4, 1); s5 += __shfl_xor(s5, 1);
    s6 += __shfl_xor(s6, 1); s7 += __shfl_xor(s7, 1); s8 += __shfl_xor(s8, 1);
    hn += __shfl_xor(hn, 1);

    if (chalf == 0) {
        invL[(h + 1) * 32 + w] = (s4 > 0.f) ? (1.0f / sqrtf(s4)) : 0.f;
        if (h == 0) invL[w]       = (hn > 0.f) ? (1.0f / sqrtf(hn)) : 0.f;
        if (h == 3) invL[160 + w] = (hn > 0.f) ? (1.0f / sqrtf(hn)) : 0.f;
    }
    __syncthreads();

    float simreg;
    {
        const float mL = (w > 0)  ? 1.f : 0.f;
        const float mR = (w < 31) ? 1.f : 0.f;
        const float* iT = invL + h * 32;
        const float* iM = iT + 32;
        const float* iB = iM + 32;
        float acc;
        acc = s0 * (iT[wm] * mL);
        acc = fmaf(s1, iT[w],       acc);
        acc = fmaf(s2, iT[wp] * mR, acc);
        acc = fmaf(s3, iM[wm] * mL, acc);
        acc = fmaf(s4, iM[w],       acc);
        acc = fmaf(s5, iM[wp] * mR, acc);
        acc = fmaf(s6, iB[wm] * mL, acc);
        acc = fmaf(s7, iB[w],       acc);
        acc = fmaf(s8, iB[wp] * mR, acc);
        simreg = acc * iM[w] * (1.0f / 9.0f);
    }
    __syncthreads();   // all waves past slab use before tile overwrite

    // ---- phase 3: aligned exchange tile T[128 pos][36] (r14-verified) ----
    float* T = shbuf;
    #pragma unroll
    for (int cb = 0; cb < 4; ++cb) {
        #pragma unroll
        for (int m = 0; m < 4; ++m) {
            float4 kk = keep[cb * 4 + m];
            kk.x *= simreg; kk.y *= simreg; kk.z *= simreg; kk.w *= simreg;
            const int qbase = pos * 36 + m * 4 + chalf * 2;   // even -> 8B aligned
            *(float2*)&T[qbase]      = make_float2(kk.x, kk.z);   // t = 0
            *(float2*)&T[qbase + 16] = make_float2(kk.y, kk.w);   // t = 1
        }
        __syncthreads();
        #pragma unroll
        for (int stp = 0; stp < 4; ++stp) {
            const int flat = stp * 256 + tid;
            const int qf = flat & 3;
            const int t  = (flat >> 2) & 1;
            const int pp = flat >> 3;
            const int hh = pp >> 5;
            const int ww = pp & 31;
            const float4 o = *(const float4*)&T[pp * 36 + t * 16 + qf * 4];
            *(float4*)(out + (size_t)b * 131072 + (size_t)t * 65536 +
                       (size_t)(r0 + hh) * 2048 + ww * 64 + cb * 16 + qf * 4) = o;
        }
        __syncthreads();
    }
}

extern "C" void kernel_launch(void* const* d_in, const int* in_sizes, int n_in,
                              void* d_out, int out_size, void* d_ws, size_t ws_size,
                              hipStream_t stream) {
    const float* p = (const float*)d_in[0];
    float* out = (float*)d_out;
    bcim_fused<<<dim3(2048), dim3(256), 0, stream>>>(p, out);
    (void)in_sizes; (void)n_in; (void)out_size; (void)d_ws; (void)ws_size;
}

// Round 16
// 60.709 us; speedup vs baseline: 1.0393x; 1.0393x over previous
//
#include <hip/hip_runtime.h>
#include <hip/hip_fp16.h>

// r14 base (59.6 us best) + ONE change: keep[16] (64 VGPR of retained p-quads)
// packed to f16 pairs (32 VGPR) via v_cvt_pkrtz. Rounds 10-15 proved the
// allocator pins 64-68 VGPR for this kernel shape regardless of hints, spilling
// ~30 floats (WRITE 163 vs 134 ideal). Shrinking the live set is the only lever
// left. f16 error on the final p*sim product: ~2e-3 added, threshold 1.7e-2.
//  phase 1: 16 chunks of 8 ch through XOR-swizzled slab, 2-deep reg prefetch,
//           9 sums S_d = sum_c p[x]*p[x+d] (full f32), retain center quads f16.
//  phase 2: inv = 1/sqrt(S_center) (+halo), sim = (1/9)*inv*sum_d inv[x+d]*S_d.
//  phase 3: aligned stride-36 exchange tile (r14-verified).

__device__ __forceinline__ float dot4acc(float4 a, float4 b, float acc) {
    acc = fmaf(a.x, b.x, acc);
    acc = fmaf(a.y, b.y, acc);
    acc = fmaf(a.z, b.z, acc);
    acc = fmaf(a.w, b.w, acc);
    return acc;
}

__global__ __launch_bounds__(256) void bcim_fused(const float* __restrict__ p,
                                                  float* __restrict__ out) {
    __shared__ float shbuf[4608];   // phase1: slab [6][64 quads][4] (1536 f); phase3: T[128][36]
    __shared__ float invL[192];

    const int tid = threadIdx.x;
    const int b  = blockIdx.x >> 3;
    const int r0 = (blockIdx.x & 7) << 2;
    const float* __restrict__ pb = p + (size_t)b * 131072;
    float* slab = shbuf;

    // ---- loader mapping (v3-verified) ----
    const int l_wq = tid & 7;
    const int l_c  = (tid >> 3) & 7;
    const int l_r  = tid >> 6;
    const int g0r  = r0 - 1 + l_r;
    const int g1r  = r0 + 3 + l_r;
    const bool in0 = ((unsigned)g0r < 32u);
    const bool in1 = (tid < 128) && ((unsigned)g1r < 32u);
    int wOff[4];
    {
        const int chh = l_c >> 2;
        const int ci  = l_c & 3;
        #pragma unroll
        for (int j = 0; j < 4; ++j) {
            const int u = ((l_wq << 3) + (j << 1) + chh) ^ l_wq;
            wOff[j] = l_r * 256 + u * 4 + ci;
        }
    }
    const int gOff0 = l_c * 1024 + g0r * 32 + l_wq * 4;
    const int gOff1 = l_c * 1024 + g1r * 32 + l_wq * 4;

    // ---- stencil mapping (v3-verified) ----
    const int chalf = tid & 1;
    const int pos   = tid >> 1;
    const int h     = pos >> 5;
    const int w     = pos & 31;
    const int wm    = (w > 0) ? w - 1 : 0;
    const int wp    = (w < 31) ? w + 1 : 31;
    const int uc    = (w  * 2 + chalf) ^ (w  >> 2);
    const int um    = (wm * 2 + chalf) ^ (wm >> 2);
    const int up    = (wp * 2 + chalf) ^ (wp >> 2);

    // 2-deep prefetch (A = even chunks, B = odd chunks)
    float4 A0 = make_float4(0.f,0.f,0.f,0.f), A1 = A0, B0 = A0, B1 = A0;
    if (in0) A0 = *(const float4*)(pb + gOff0);
    if (in1) A1 = *(const float4*)(pb + gOff1);
    if (in0) B0 = *(const float4*)(pb + 8192 + gOff0);
    if (in1) B1 = *(const float4*)(pb + 8192 + gOff1);

    float s0=0.f,s1=0.f,s2=0.f,s3=0.f,s4=0.f,s5=0.f,s6=0.f,s7=0.f,s8=0.f,hn=0.f;
    __half2 kA[16], kB[16];   // packed retained center quads (32 VGPR total)

    #define STEP(R0, R1, NEXTC, CUR) {                                              \
        slab[wOff[0]] = R0.x; slab[wOff[1]] = R0.y;                                 \
        slab[wOff[2]] = R0.z; slab[wOff[3]] = R0.w;                                 \
        if (tid < 128) {                                                            \
            slab[wOff[0] + 1024] = R1.x; slab[wOff[1] + 1024] = R1.y;               \
            slab[wOff[2] + 1024] = R1.z; slab[wOff[3] + 1024] = R1.w;               \
        }                                                                           \
        __syncthreads();                                                            \
        if ((NEXTC) < 16) {                                                         \
            if (in0) R0 = *(const float4*)(pb + (NEXTC) * 8192 + gOff0);            \
            if (in1) R1 = *(const float4*)(pb + (NEXTC) * 8192 + gOff1);            \
        }                                                                           \
        {                                                                           \
            const float4* sp = (const float4*)slab;                                 \
            const float4 ctr = sp[(h + 1) * 64 + uc];                               \
            kA[CUR] = __floats2half2_rn(ctr.x, ctr.y);                              \
            kB[CUR] = __floats2half2_rn(ctr.z, ctr.w);                              \
            float4 n0 = sp[h * 64 + um];                                            \
            float4 n1 = sp[h * 64 + uc];                                            \
            float4 n2 = sp[h * 64 + up];                                            \
            s0 = dot4acc(ctr, n0, s0);                                              \
            s1 = dot4acc(ctr, n1, s1);                                              \
            s2 = dot4acc(ctr, n2, s2);                                              \
            if (h == 0) hn = dot4acc(n1, n1, hn);                                   \
            n0 = sp[(h + 2) * 64 + um];                                             \
            n1 = sp[(h + 2) * 64 + uc];                                             \
            n2 = sp[(h + 2) * 64 + up];                                             \
            s6 = dot4acc(ctr, n0, s6);                                              \
            s7 = dot4acc(ctr, n1, s7);                                              \
            s8 = dot4acc(ctr, n2, s8);                                              \
            if (h == 3) hn = dot4acc(n1, n1, hn);                                   \
            n0 = sp[(h + 1) * 64 + um];                                             \
            n2 = sp[(h + 1) * 64 + up];                                             \
            s3 = dot4acc(ctr, n0, s3);                                              \
            s4 = dot4acc(ctr, ctr, s4);                                             \
            s5 = dot4acc(ctr, n2, s5);                                              \
        }                                                                           \
        __syncthreads(); }

    #pragma unroll
    for (int ch = 0; ch < 16; ch += 2) {
        STEP(A0, A1, ch + 2, ch)
        STEP(B0, B1, ch + 3, ch + 1)
    }
    #undef STEP

    // pair-reduce channel halves (lanes 2k <-> 2k+1): both lanes get full sums
    s0 += __shfl_xor(s0, 1); s1 += __shfl_xor(s1, 1); s2 += __shfl_xor(s2, 1);
    s3 += __shfl_xor(s3, 1); s4 += __shfl_xor(s4, 1); s5 += __shfl_xor(s5, 1);
    s6 += __shfl_xor(s6, 1); s7 += __shfl_xor(s7, 1); s8 += __shfl_xor(s8, 1);
    hn += __shfl_xor(hn, 1);

    if (chalf == 0) {
        invL[(h + 1) * 32 + w] = (s4 > 0.f) ? (1.0f / sqrtf(s4)) : 0.f;
        if (h == 0) invL[w]       = (hn > 0.f) ? (1.0f / sqrtf(hn)) : 0.f;
        if (h == 3) invL[160 + w] = (hn > 0.f) ? (1.0f / sqrtf(hn)) : 0.f;
    }
    __syncthreads();

    float simreg;
    {
        const float mL = (w > 0)  ? 1.f : 0.f;
        const float mR = (w < 31) ? 1.f : 0.f;
        const float* iT = invL + h * 32;
        const float* iM = iT + 32;
        const float* iB = iM + 32;
        float acc;
        acc = s0 * (iT[wm] * mL);
        acc = fmaf(s1, iT[w],       acc);
        acc = fmaf(s2, iT[wp] * mR, acc);
        acc = fmaf(s3, iM[wm] * mL, acc);
        acc = fmaf(s4, iM[w],       acc);
        acc = fmaf(s5, iM[wp] * mR, acc);
        acc = fmaf(s6, iB[wm] * mL, acc);
        acc = fmaf(s7, iB[w],       acc);
        acc = fmaf(s8, iB[wp] * mR, acc);
        simreg = acc * iM[w] * (1.0f / 9.0f);
    }
    __syncthreads();   // all waves past slab use before tile overwrite

    // ---- phase 3: aligned exchange tile T[128 pos][36] (r14-verified) ----
    float* T = shbuf;
    #pragma unroll
    for (int cb = 0; cb < 4; ++cb) {
        #pragma unroll
        for (int m = 0; m < 4; ++m) {
            const float2 lo = __half22float2(kA[cb * 4 + m]);
            const float2 hi = __half22float2(kB[cb * 4 + m]);
            float4 kk = make_float4(lo.x, lo.y, hi.x, hi.y);
            kk.x *= simreg; kk.y *= simreg; kk.z *= simreg; kk.w *= simreg;
            const int qbase = pos * 36 + m * 4 + chalf * 2;   // even -> 8B aligned
            *(float2*)&T[qbase]      = make_float2(kk.x, kk.z);   // t = 0
            *(float2*)&T[qbase + 16] = make_float2(kk.y, kk.w);   // t = 1
        }
        __syncthreads();
        #pragma unroll
        for (int stp = 0; stp < 4; ++stp) {
            const int flat = stp * 256 + tid;
            const int qf = flat & 3;
            const int t  = (flat >> 2) & 1;
            const int pp = flat >> 3;
            const int hh = pp >> 5;
            const int ww = pp & 31;
            const float4 o = *(const float4*)&T[pp * 36 + t * 16 + qf * 4];
            *(float4*)(out + (size_t)b * 131072 + (size_t)t * 65536 +
                       (size_t)(r0 + hh) * 2048 + ww * 64 + cb * 16 + qf * 4) = o;
        }
        __syncthreads();
    }
}

extern "C" void kernel_launch(void* const* d_in, const int* in_sizes, int n_in,
                              void* d_out, int out_size, void* d_ws, size_t ws_size,
                              hipStream_t stream) {
    const float* p = (const float*)d_in[0];
    float* out = (float*)d_out;
    bcim_fused<<<dim3(2048), dim3(256), 0, stream>>>(p, out);
    (void)in_sizes; (void)n_in; (void)out_size; (void)d_ws; (void)ws_size;
}

// Round 17
// 59.736 us; speedup vs baseline: 1.0562x; 1.0163x over previous
//
#include <hip/hip_runtime.h>
#include <hip/hip_fp16.h>

// 512-thread restructure of r14 (59.6 us best). Per (b, 4-row strip):
//  4 lanes per position: (chalf = tid&1, cgroup = (tid>>1)&1, pos = tid>>2).
//  Each cgroup processes 8 chunks (channels cgroup*64..+63) from its OWN slab;
//  two slabs staged per step (8 steps). Per-thread live state ~58 floats
//  (kA/kB[8] f16 + 1-deep prefetch + 10 sums) -> fits the 64-VGPR budget the
//  allocator insists on (r10-r16: every 256-thread variant spilled 26-45 MB).
//  Sums reduced via shfl_xor(1) then shfl_xor(2). Phase 3 = r14's verified
//  aligned stride-36 exchange tile; writers = the cb-matching cgroup half.

__device__ __forceinline__ float dot4acc(float4 a, float4 b, float acc) {
    acc = fmaf(a.x, b.x, acc);
    acc = fmaf(a.y, b.y, acc);
    acc = fmaf(a.z, b.z, acc);
    acc = fmaf(a.w, b.w, acc);
    return acc;
}

__global__ __launch_bounds__(512) void bcim_fused(const float* __restrict__ p,
                                                  float* __restrict__ out) {
    __shared__ float shbuf[4608];   // phase1: 2 slabs [6][64 quads][4] (3072 f); phase3: T[128][36]
    __shared__ float invL[192];

    const int tid = threadIdx.x;
    const int b  = blockIdx.x >> 3;
    const int r0 = (blockIdx.x & 7) << 2;
    const float* __restrict__ pb = p + (size_t)b * 131072;
    float* slab = shbuf;

    // ---- loader slots: slot0 = idx tid (all), slot1 = idx 512+tid (tid<256) ----
    // idx -> (wq = idx&7, c8 = (idx>>3)&7, r = (idx>>6)%6, slab = idx/384)
    const int s0wq = tid & 7, s0c = (tid >> 3) & 7, s0r = (tid >> 6) % 6, s0s = tid / 384;
    const int i1   = 512 + tid;
    const int s1wq = i1 & 7,  s1c = (i1 >> 3) & 7,  s1r = (i1 >> 6) % 6;   // slab 1 always
    const int g0row = r0 - 1 + s0r;
    const int g1row = r0 - 1 + s1r;
    const bool ok0 = ((unsigned)g0row < 32u);                  // wave-uniform
    const bool ok1 = (tid < 256) && ((unsigned)g1row < 32u);   // wave-uniform
    int w0Off[4], w1Off[4];
    {
        const int ch0 = s0c >> 2, ci0 = s0c & 3;
        const int ch1 = s1c >> 2, ci1 = s1c & 3;
        #pragma unroll
        for (int j = 0; j < 4; ++j) {
            const int u0 = ((s0wq << 3) + (j << 1) + ch0) ^ s0wq;
            const int u1 = ((s1wq << 3) + (j << 1) + ch1) ^ s1wq;
            w0Off[j] = s0s * 1536 + s0r * 256 + u0 * 4 + ci0;
            w1Off[j] = 1536 + s1r * 256 + u1 * 4 + ci1;
        }
    }
    const int gB0 = (s0s * 64 + s0c) * 1024 + g0row * 32 + s0wq * 4;
    const int gB1 = (64 + s1c) * 1024 + g1row * 32 + s1wq * 4;

    // ---- stencil mapping ----
    const int chalf = tid & 1;
    const int cgrp  = (tid >> 1) & 1;
    const int pos   = tid >> 2;          // 0..127
    const int h     = pos >> 5;          // wave-uniform
    const int w     = pos & 31;
    const int wm    = (w > 0) ? w - 1 : 0;
    const int wp    = (w < 31) ? w + 1 : 31;
    const int uc    = (w  * 2 + chalf) ^ (w  >> 2);
    const int um    = (wm * 2 + chalf) ^ (wm >> 2);
    const int up    = (wp * 2 + chalf) ^ (wp >> 2);
    const float4* spC = (const float4*)(slab + cgrp * 1536);

    float4 st0 = make_float4(0.f, 0.f, 0.f, 0.f), st1 = st0;
    if (ok0) st0 = *(const float4*)(pb + gB0);
    if (ok1) st1 = *(const float4*)(pb + gB1);

    float s0=0.f,s1=0.f,s2=0.f,s3=0.f,s4=0.f,s5=0.f,s6=0.f,s7=0.f,s8=0.f,hn=0.f;
    __half2 kA[8], kB[8];

    #pragma unroll
    for (int stp = 0; stp < 8; ++stp) {
        slab[w0Off[0]] = st0.x; slab[w0Off[1]] = st0.y;
        slab[w0Off[2]] = st0.z; slab[w0Off[3]] = st0.w;
        if (tid < 256) {
            slab[w1Off[0]] = st1.x; slab[w1Off[1]] = st1.y;
            slab[w1Off[2]] = st1.z; slab[w1Off[3]] = st1.w;
        }
        __syncthreads();
        if (stp < 7) {      // issue next step's loads; latency hides under stencil
            if (ok0) st0 = *(const float4*)(pb + (stp + 1) * 8192 + gB0);
            if (ok1) st1 = *(const float4*)(pb + (stp + 1) * 8192 + gB1);
        }
        {
            const float4 ctr = spC[(h + 1) * 64 + uc];
            kA[stp] = __floats2half2_rn(ctr.x, ctr.y);
            kB[stp] = __floats2half2_rn(ctr.z, ctr.w);
            float4 n0 = spC[h * 64 + um];
            float4 n1 = spC[h * 64 + uc];
            float4 n2 = spC[h * 64 + up];
            s0 = dot4acc(ctr, n0, s0);
            s1 = dot4acc(ctr, n1, s1);
            s2 = dot4acc(ctr, n2, s2);
            if (h == 0) hn = dot4acc(n1, n1, hn);
            n0 = spC[(h + 2) * 64 + um];
            n1 = spC[(h + 2) * 64 + uc];
            n2 = spC[(h + 2) * 64 + up];
            s6 = dot4acc(ctr, n0, s6);
            s7 = dot4acc(ctr, n1, s7);
            s8 = dot4acc(ctr, n2, s8);
            if (h == 3) hn = dot4acc(n1, n1, hn);
            n0 = spC[(h + 1) * 64 + um];
            n2 = spC[(h + 1) * 64 + up];
            s3 = dot4acc(ctr, n0, s3);
            s4 = dot4acc(ctr, ctr, s4);
            s5 = dot4acc(ctr, n2, s5);
        }
        __syncthreads();
    }

    // reduce over chalf (xor 1) then cgroup (xor 2): all 4 lanes get full sums
    s0 += __shfl_xor(s0, 1); s1 += __shfl_xor(s1, 1); s2 += __shfl_xor(s2, 1);
    s3 += __shfl_xor(s3, 1); s4 += __shfl_xor(s4, 1); s5 += __shfl_xor(s5, 1);
    s6 += __shfl_xor(s6, 1); s7 += __shfl_xor(s7, 1); s8 += __shfl_xor(s8, 1);
    hn += __shfl_xor(hn, 1);
    s0 += __shfl_xor(s0, 2); s1 += __shfl_xor(s1, 2); s2 += __shfl_xor(s2, 2);
    s3 += __shfl_xor(s3, 2); s4 += __shfl_xor(s4, 2); s5 += __shfl_xor(s5, 2);
    s6 += __shfl_xor(s6, 2); s7 += __shfl_xor(s7, 2); s8 += __shfl_xor(s8, 2);
    hn += __shfl_xor(hn, 2);

    if ((tid & 3) == 0) {
        invL[(h + 1) * 32 + w] = (s4 > 0.f) ? (1.0f / sqrtf(s4)) : 0.f;
        if (h == 0) invL[w]       = (hn > 0.f) ? (1.0f / sqrtf(hn)) : 0.f;
        if (h == 3) invL[160 + w] = (hn > 0.f) ? (1.0f / sqrtf(hn)) : 0.f;
    }
    __syncthreads();

    float simreg;
    {
        const float mL = (w > 0)  ? 1.f : 0.f;
        const float mR = (w < 31) ? 1.f : 0.f;
        const float* iT = invL + h * 32;
        const float* iM = iT + 32;
        const float* iB = iM + 32;
        float acc;
        acc = s0 * (iT[wm] * mL);
        acc = fmaf(s1, iT[w],       acc);
        acc = fmaf(s2, iT[wp] * mR, acc);
        acc = fmaf(s3, iM[wm] * mL, acc);
        acc = fmaf(s4, iM[w],       acc);
        acc = fmaf(s5, iM[wp] * mR, acc);
        acc = fmaf(s6, iB[wm] * mL, acc);
        acc = fmaf(s7, iB[w],       acc);
        acc = fmaf(s8, iB[wp] * mR, acc);
        simreg = acc * iM[w] * (1.0f / 9.0f);
    }

    // ---- phase 3: aligned exchange tile T[128 pos][36] (r14-verified) ----
    // chunk ch = cb*4 + m is owned by cgroup ch>>3 = cb>>1, local ki = (cb&1)*4 + m.
    float* T = shbuf;
    #pragma unroll
    for (int cb = 0; cb < 4; ++cb) {
        if (cgrp == (cb >> 1)) {
            #pragma unroll
            for (int m = 0; m < 4; ++m) {
                const int ki = (cb & 1) * 4 + m;
                const float2 lo = __half22float2(kA[ki]);
                const float2 hi = __half22float2(kB[ki]);
                float4 kk = make_float4(lo.x, lo.y, hi.x, hi.y);
                kk.x *= simreg; kk.y *= simreg; kk.z *= simreg; kk.w *= simreg;
                const int qbase = pos * 36 + m * 4 + chalf * 2;   // even -> aligned
                *(float2*)&T[qbase]      = make_float2(kk.x, kk.z);   // t = 0
                *(float2*)&T[qbase + 16] = make_float2(kk.y, kk.w);   // t = 1
            }
        }
        __syncthreads();
        #pragma unroll
        for (int stp = 0; stp < 2; ++stp) {
            const int flat = stp * 512 + tid;
            const int qf = flat & 3;
            const int t  = (flat >> 2) & 1;
            const int pp = flat >> 3;
            const int hh = pp >> 5;
            const int ww = pp & 31;
            const float4 o = *(const float4*)&T[pp * 36 + t * 16 + qf * 4];
            *(float4*)(out + (size_t)b * 131072 + (size_t)t * 65536 +
                       (size_t)(r0 + hh) * 2048 + ww * 64 + cb * 16 + qf * 4) = o;
        }
        __syncthreads();
    }
}

extern "C" void kernel_launch(void* const* d_in, const int* in_sizes, int n_in,
                              void* d_out, int out_size, void* d_ws, size_t ws_size,
                              hipStream_t stream) {
    const float* p = (const float*)d_in[0];
    float* out = (float*)d_out;
    bcim_fused<<<dim3(2048), dim3(512), 0, stream>>>(p, out);
    (void)in_sizes; (void)n_in; (void)out_size; (void)d_ws; (void)ws_size;
}